// Round 18
// baseline (443.264 us; speedup 1.0000x reference)
//
#include <hip/hip_runtime.h>
#include <hip/hip_bf16.h>

// BS=64 NQ=900 L=1024 D=768 H=256 E=8 TOPK=2 MOE_W=0.5
// out: (64,900,1024) f32
// Sparse MoE: heterogeneous fused front-end, hierarchical bucketing, expert
// gather-GEMM, proj GEMM fused with combine, logit GEMM = full-K LDS residency
// (2 deep phases x 64 MFMA/wave, counted vmcnt, 2 barriers total, XCD-pinned).
// LAUNCH-BOUNDS LESSON (r14/15): GEMMs are register-pinned; min-waves above
// natural allocation forces VGPR < acc[4][4]'s 64 and spills (3x slowdown).

typedef __attribute__((ext_vector_type(8))) short bf16x8;
typedef __attribute__((ext_vector_type(4))) float f32x4;

#define NROW 65536            // 64*1024 token rows
#define CAP  65536            // per-expert bucket capacity (worst case)
#define CSTRIDE 16            // cnt padding: one counter per 64B line
#define SWZ(r) ((((r) & 3) ^ (((r) >> 2) & 3)))

// fused front-end grid partition (k1 first: long pole starts immediately)
#define NB_K1 2048
#define NB_KX 14400
#define NB_K0 432             // 12 x 4 x 9
#define NB_KZ 9

__device__ __forceinline__ unsigned short f2bf(float f) {
    unsigned u = __builtin_bit_cast(unsigned, f);
    u += 0x7fffu + ((u >> 16) & 1u);   // RNE; inputs finite
    return (unsigned short)(u >> 16);
}
__device__ __forceinline__ float bf2f(unsigned short h) {
    unsigned u = ((unsigned)h) << 16;
    return __builtin_bit_cast(float, u);
}
__device__ __forceinline__ void gload16(const void* g, void* l) {
    __builtin_amdgcn_global_load_lds(
        (const __attribute__((address_space(1))) void*)g,
        (__attribute__((address_space(3))) void*)l, 16, 0, 0);
}
__device__ __forceinline__ unsigned cvt_pk_bf16(float a, float b) {
    unsigned r;
    asm("v_cvt_pk_bf16_f32 %0, %1, %2" : "=v"(r) : "v"(a), "v"(b));
    return r;
}

// ---------------------------------------------------------------- K_FRONT:
__global__ __launch_bounds__(256, 4) void k_front(
    const float* __restrict__ x, const float* __restrict__ emb_in,
    const float* __restrict__ proj_w, const float* __restrict__ proj_b,
    const float* __restrict__ gate_w, const float* __restrict__ gate_b,
    const float* __restrict__ expert_w, const float* __restrict__ expert_b,
    const float* __restrict__ bias_lang, const float* __restrict__ bias0,
    unsigned short* __restrict__ x_bf, unsigned short* __restrict__ wcatT,
    float* __restrict__ bcat, unsigned* __restrict__ cnt,
    unsigned short* __restrict__ emb_bf, unsigned* __restrict__ top2,
    float2* __restrict__ c2, float* __restrict__ tbias)
{
    __shared__ __align__(16) float smem[9 * 768];   // 27.6 KB, unioned per branch
    int bid = blockIdx.x, tid = threadIdx.x;

    if (bid < NB_K1) {
        // ---------------- k1_fused body ----------------
        float* gwT = smem;
        for (int i = tid; i < 768 * 8; i += 256) {
            int d = i >> 3, e = i & 7;
            gwT[e * 768 + d] = gate_w[i];
        }
        for (int i = tid; i < 768; i += 256)
            gwT[8 * 768 + i] = bias_lang[i];
        __syncthreads();

        int w = tid >> 6, lane = tid & 63;
        #pragma unroll 1
        for (int it = 0; it < 8; ++it) {
            int r = bid * 32 + w * 8 + it;
            const float4* rv = (const float4*)(emb_in + (size_t)r * 768);
            float4 v0 = rv[lane], v1 = rv[lane + 64], v2 = rv[lane + 128];
            float ss = v0.x*v0.x + v0.y*v0.y + v0.z*v0.z + v0.w*v0.w
                     + v1.x*v1.x + v1.y*v1.y + v1.z*v1.z + v1.w*v1.w
                     + v2.x*v2.x + v2.y*v2.y + v2.z*v2.z + v2.w*v2.w;
            #pragma unroll
            for (int m = 1; m < 64; m <<= 1) ss += __shfl_xor(ss, m, 64);
            float rn = rsqrtf(ss);

            unsigned long long q0 = (unsigned long long)cvt_pk_bf16(v0.x*rn, v0.y*rn) |
                                    ((unsigned long long)cvt_pk_bf16(v0.z*rn, v0.w*rn) << 32);
            unsigned long long q1 = (unsigned long long)cvt_pk_bf16(v1.x*rn, v1.y*rn) |
                                    ((unsigned long long)cvt_pk_bf16(v1.z*rn, v1.w*rn) << 32);
            unsigned long long q2 = (unsigned long long)cvt_pk_bf16(v2.x*rn, v2.y*rn) |
                                    ((unsigned long long)cvt_pk_bf16(v2.z*rn, v2.w*rn) << 32);
            unsigned long long* ob = (unsigned long long*)(emb_bf + (size_t)r * 768);
            __builtin_nontemporal_store(q0, ob + lane);
            __builtin_nontemporal_store(q1, ob + lane + 64);
            __builtin_nontemporal_store(q2, ob + lane + 128);

            float acc[9];
            #pragma unroll
            for (int i = 0; i < 9; i++) acc[i] = 0.f;
            const float4 vv[3] = { v0, v1, v2 };
            #pragma unroll
            for (int k = 0; k < 3; k++) {
                float4 v = vv[k];
                #pragma unroll
                for (int e = 0; e < 9; e++) {
                    float4 g = *(const float4*)&gwT[e * 768 + k * 256 + lane * 4];
                    acc[e] += v.x*g.x + v.y*g.y + v.z*g.z + v.w*g.w;
                }
            }
            #pragma unroll
            for (int m = 1; m < 64; m <<= 1) {
                #pragma unroll
                for (int i = 0; i < 9; i++) acc[i] += __shfl_xor(acc[i], m, 64);
            }
            if (lane == 0) {
                float g[8];
                #pragma unroll
                for (int e = 0; e < 8; e++) g[e] = acc[e] * rn + gate_b[e];
                float mx = g[0];
                #pragma unroll
                for (int e = 1; e < 8; e++) mx = fmaxf(mx, g[e]);
                float p[8], s = 0.f;
                #pragma unroll
                for (int e = 0; e < 8; e++) { p[e] = __expf(g[e] - mx); s += p[e]; }
                float inv = 0.5f / s;
                int i1 = 0;
                #pragma unroll
                for (int e = 1; e < 8; e++) if (g[e] > g[i1]) i1 = e;
                int i2 = (i1 == 0) ? 1 : 0;
                #pragma unroll
                for (int e = 0; e < 8; e++) if (e != i1 && g[e] > g[i2]) i2 = e;
                top2[r] = (unsigned)i1 | ((unsigned)i2 << 8);
                c2[r]   = make_float2(p[i1] * inv, p[i2] * inv);
                tbias[r] = acc[8] * rn + bias0[0];
            }
        }
    } else if (bid < NB_K1 + NB_KX) {
        // ---------------- kx_cast body ----------------
        int i = (bid - NB_K1) * 256 + tid;
        float4 v = ((const float4*)x)[i];
        unsigned long long o = (unsigned long long)cvt_pk_bf16(v.x, v.y) |
                               ((unsigned long long)cvt_pk_bf16(v.z, v.w) << 32);
        __builtin_nontemporal_store(o, (unsigned long long*)x_bf + i);
    } else if (bid < NB_K1 + NB_KX + NB_K0) {
        // ---------------- k0_wT body ----------------
        int u = bid - NB_K1 - NB_KX;            // [0, 432)
        int j = u / 48, rem = u % 48;
        int d0 = (rem % 12) * 64, h0 = (rem / 12) * 64;
        const float* W = (j < 8) ? expert_w + (size_t)j * 768 * 256 : proj_w;
        unsigned short (*s)[65] = (unsigned short (*)[65])smem;   // 8.3 KB of 27.6
        #pragma unroll
        for (int i = 0; i < 16; i++) {
            int d = i * 4 + (tid >> 6), h = tid & 63;
            s[d][h] = f2bf(W[(size_t)(d0 + d) * 256 + h0 + h]);
        }
        __syncthreads();
        #pragma unroll
        for (int i = 0; i < 16; i++) {
            int h = i * 4 + (tid >> 6), d = tid & 63;
            wcatT[(size_t)(j * 256 + h0 + h) * 768 + d0 + d] = s[d][h];
        }
    } else {
        // ---------------- kz_misc body ----------------
        int i = (bid - NB_K1 - NB_KX - NB_K0) * 256 + tid;
        if (i < 2304) {
            int jj = i >> 8, h = i & 255;
            bcat[i] = (jj < 8) ? expert_b[jj * 256 + h] : proj_b[h];
        }
        if (i < 8 * CSTRIDE) cnt[i] = 0;
    }
}

// ---------------------------------------------------------------- KB (hierarchical):
__global__ __launch_bounds__(256) void kb_bucket(
    const unsigned* __restrict__ top2, const float2* __restrict__ c2,
    unsigned* __restrict__ cnt, unsigned* __restrict__ bidx,
    float* __restrict__ bscale)
{
    __shared__ unsigned lcnt[8];
    __shared__ unsigned gbase[8];
    int tid = threadIdx.x, lane = tid & 63;
    if (tid < 8) lcnt[tid] = 0;
    __syncthreads();
    int r = blockIdx.x * 256 + tid;
    unsigned t = top2[r];
    float2 c = c2[r];
    int ii[2] = { (int)(t & 255), (int)((t >> 8) & 255) };
    float cc[2] = { c.x, c.y };
    unsigned lpos[2];
    #pragma unroll
    for (int slot = 0; slot < 2; slot++) {
        int myE = ii[slot];
        #pragma unroll 1
        for (int e = 0; e < 8; e++) {
            unsigned long long mask = __ballot(myE == e);
            if (myE == e) {
                int leader = __ffsll((unsigned long long)mask) - 1;
                unsigned base = 0;
                if (lane == leader)
                    base = atomicAdd(&lcnt[e], (unsigned)__popcll(mask));
                base = __shfl(base, leader, 64);
                lpos[slot] = base + (unsigned)__popcll(mask & ((1ull << lane) - 1ull));
            }
        }
    }
    __syncthreads();
    if (tid < 8) gbase[tid] = atomicAdd(&cnt[tid * CSTRIDE], lcnt[tid]);
    __syncthreads();
    #pragma unroll
    for (int slot = 0; slot < 2; slot++) {
        int e = ii[slot];
        unsigned p = gbase[e] + lpos[slot];
        bidx[(size_t)e * CAP + p]   = (unsigned)r | ((unsigned)slot << 16);
        bscale[(size_t)e * CAP + p] = cc[slot];
    }
}

// ---------------------------------------------------------------- K2E (experts 0..7):
__global__ __launch_bounds__(512, 2) void k2_expert(
    const unsigned short* __restrict__ emb_bf, const unsigned short* __restrict__ wcatT,
    const float* __restrict__ bcat, const unsigned* __restrict__ cnt,
    const unsigned* __restrict__ bidx, const float* __restrict__ bscale,
    unsigned short* __restrict__ partial)
{
    int e = blockIdx.y;                 // 0..7
    int tile = blockIdx.x;
    int cnt_e = (int)cnt[e * CSTRIDE];
    if (tile * 128 >= cnt_e) return;
    int tid = threadIdx.x, lane = tid & 63, w = tid >> 6;
    int wm = w >> 2, wn = w & 3;
    __shared__ __align__(16) unsigned short As[2][128 * 32];   // 16 KB
    __shared__ __align__(16) unsigned short Bs[2][256 * 32];   // 32 KB
    __shared__ unsigned sRow[128];
    __shared__ float sScale[128];
    if (tid < 128) {
        int gi = tile * 128 + tid;
        unsigned rs; float sc;
        if (gi < cnt_e) { rs = bidx[(size_t)e * CAP + gi];
                          sc = bscale[(size_t)e * CAP + gi]; }
        else            { rs = 0; sc = 0.f; }
        sRow[tid] = rs; sScale[tid] = sc;
    }
    __syncthreads();
    int r16 = lane & 15, r4 = lane >> 4;
    int srowA = tid >> 2, ssegA = (tid & 3) ^ SWZ(srowA);
    const unsigned short* aSrc =
        emb_bf + (size_t)(sRow[srowA] & 0xFFFFu) * 768 + ssegA * 8;
    const unsigned short* bBase = wcatT + (size_t)e * 256 * 768;

    auto stageA = [&](int kt, int buf) {
        gload16(aSrc + kt * 32, &As[buf][w * 512]);
    };
    auto stageB = [&](int kt, int buf) {
        #pragma unroll
        for (int i = 0; i < 2; i++) {
            int u = i * 512 + tid;
            int brow = u >> 2, seg = (u & 3) ^ SWZ(brow);
            gload16(&bBase[(size_t)brow * 768 + kt * 32 + seg * 8],
                    &Bs[buf][i * 4096 + w * 512]);
        }
    };

    f32x4 acc[4][4];
    #pragma unroll
    for (int mi = 0; mi < 4; mi++)
        #pragma unroll
        for (int ni = 0; ni < 4; ni++) acc[mi][ni] = f32x4{0.f, 0.f, 0.f, 0.f};

    stageA(0, 0); stageB(0, 0);
    __syncthreads();
    int buf = 0;
    #pragma unroll 1
    for (int kt = 0; kt < 24; ++kt) {
        if (kt < 23) { stageA(kt + 1, buf ^ 1); stageB(kt + 1, buf ^ 1); }
        bf16x8 a[4], b[4];
        #pragma unroll
        for (int mi = 0; mi < 4; mi++) {
            int arow = wm * 64 + mi * 16 + r16;
            a[mi] = *(const bf16x8*)&As[buf][arow * 32 + (r4 ^ SWZ(arow)) * 8];
        }
        #pragma unroll
        for (int ni = 0; ni < 4; ni++) {
            int brow = wn * 64 + ni * 16 + r16;
            b[ni] = *(const bf16x8*)&Bs[buf][brow * 32 + (r4 ^ SWZ(brow)) * 8];
        }
        #pragma unroll
        for (int mi = 0; mi < 4; mi++)
            #pragma unroll
            for (int ni = 0; ni < 4; ni++)
                acc[mi][ni] = __builtin_amdgcn_mfma_f32_16x16x32_bf16(
                    a[mi], b[ni], acc[mi][ni], 0, 0, 0);
        __syncthreads();
        buf ^= 1;
    }

    float bj[4];
    #pragma unroll
    for (int ni = 0; ni < 4; ni++) bj[ni] = bcat[e * 256 + wn * 64 + ni * 16 + r16];
    #pragma unroll
    for (int mi = 0; mi < 4; mi++) {
        #pragma unroll
        for (int e4 = 0; e4 < 4; e4++) {
            int rl = wm * 64 + mi * 16 + r4 * 4 + e4;
            if (tile * 128 + rl < cnt_e) {
                unsigned rs = sRow[rl];
                float sc = sScale[rl];
                unsigned rowg = rs & 0xFFFFu, slot = rs >> 16;
                #pragma unroll
                for (int ni = 0; ni < 4; ni++) {
                    int col = wn * 64 + ni * 16 + r16;
                    __builtin_nontemporal_store(
                        f2bf(sc * (acc[mi][ni][e4] + bj[ni])),
                        &partial[((size_t)slot * NROW + rowg) * 256 + col]);
                }
            }
        }
    }
}

// ---------------------------------------------------------------- K2P (proj + combine):
__global__ __launch_bounds__(512, 2) void k2_proj(
    const unsigned short* __restrict__ emb_bf, const unsigned short* __restrict__ wcatT,
    const float* __restrict__ bcat, const unsigned short* __restrict__ partial,
    unsigned short* __restrict__ tokens)
{
    int tile = blockIdx.x;
    int tid = threadIdx.x, lane = tid & 63, w = tid >> 6;
    int wm = w >> 2, wn = w & 3;
    int rowBase = tile * 128;
    __shared__ __align__(16) unsigned short As[2][128 * 32];
    __shared__ __align__(16) unsigned short Bs[2][256 * 32];
    int r16 = lane & 15, r4 = lane >> 4;
    int srowA = tid >> 2, ssegA = (tid & 3) ^ SWZ(srowA);
    const unsigned short* aSrc =
        emb_bf + (size_t)(rowBase + srowA) * 768 + ssegA * 8;
    const unsigned short* bBase = wcatT + (size_t)8 * 256 * 768;

    auto stageA = [&](int kt, int buf) {
        gload16(aSrc + kt * 32, &As[buf][w * 512]);
    };
    auto stageB = [&](int kt, int buf) {
        #pragma unroll
        for (int i = 0; i < 2; i++) {
            int u = i * 512 + tid;
            int brow = u >> 2, seg = (u & 3) ^ SWZ(brow);
            gload16(&bBase[(size_t)brow * 768 + kt * 32 + seg * 8],
                    &Bs[buf][i * 4096 + w * 512]);
        }
    };

    f32x4 acc[4][4];
    #pragma unroll
    for (int mi = 0; mi < 4; mi++)
        #pragma unroll
        for (int ni = 0; ni < 4; ni++) acc[mi][ni] = f32x4{0.f, 0.f, 0.f, 0.f};

    stageA(0, 0); stageB(0, 0);
    __syncthreads();
    int buf = 0;
    #pragma unroll 1
    for (int kt = 0; kt < 24; ++kt) {
        if (kt < 23) { stageA(kt + 1, buf ^ 1); stageB(kt + 1, buf ^ 1); }
        bf16x8 a[4], b[4];
        #pragma unroll
        for (int mi = 0; mi < 4; mi++) {
            int arow = wm * 64 + mi * 16 + r16;
            a[mi] = *(const bf16x8*)&As[buf][arow * 32 + (r4 ^ SWZ(arow)) * 8];
        }
        #pragma unroll
        for (int ni = 0; ni < 4; ni++) {
            int brow = wn * 64 + ni * 16 + r16;
            b[ni] = *(const bf16x8*)&Bs[buf][brow * 32 + (r4 ^ SWZ(brow)) * 8];
        }
        #pragma unroll
        for (int mi = 0; mi < 4; mi++)
            #pragma unroll
            for (int ni = 0; ni < 4; ni++)
                acc[mi][ni] = __builtin_amdgcn_mfma_f32_16x16x32_bf16(
                    a[mi], b[ni], acc[mi][ni], 0, 0, 0);
        __syncthreads();
        buf ^= 1;
    }

    const size_t S = (size_t)NROW * 256;
    float bj[4];
    #pragma unroll
    for (int ni = 0; ni < 4; ni++) bj[ni] = bcat[8 * 256 + wn * 64 + ni * 16 + r16];
    #pragma unroll
    for (int mi = 0; mi < 4; mi++) {
        #pragma unroll
        for (int e4 = 0; e4 < 4; e4++) {
            int rl = wm * 64 + mi * 16 + r4 * 4 + e4;
            size_t rowg = rowBase + rl;
            #pragma unroll
            for (int ni = 0; ni < 4; ni++) {
                int col = wn * 64 + ni * 16 + r16;
                float p0 = bf2f(partial[rowg * 256 + col]);
                float p1 = bf2f(partial[S + rowg * 256 + col]);
                float v = 0.5f * (acc[mi][ni][e4] + bj[ni]) + p0 + p1;
                __builtin_nontemporal_store(f2bf(v), &tokens[rowg * 256 + col]);
            }
        }
    }
}

// ---------------------------------------------------------------- K3 (full-K LDS, 2 deep phases, XCD-pinned):
// A+B panels for all K=256 in LDS (2 halves x 64KB = 128KB, 1 block/CU).
// Issue all 32 loads/thread up-front; vmcnt(16) -> barrier -> 64 MFMA/wave on
// half 0 (half 1 loads in flight underneath) -> vmcnt(0) -> barrier -> 64 MFMA.
// Seg swizzle: phys = seg ^ (row&15) over 16 segs/half-row (2-way max, free).
__global__ __launch_bounds__(256) void k3_logit(
    const unsigned short* __restrict__ x_bf, const unsigned short* __restrict__ tokens,
    const float* __restrict__ tbias, const float* __restrict__ log_scale,
    float* __restrict__ out)
{
    int wgid = blockIdx.x;
    int xcd = wgid & 7, slot = wgid >> 3;
    int b = xcd + 8 * (slot >> 6);
    int t64 = slot & 63;
    int tm = t64 >> 3, tn = t64 & 7;

    int tid = threadIdx.x, lane = tid & 63, w = tid >> 6;
    int wm = w >> 1, wn = w & 1;
    __shared__ __align__(16) unsigned short As[2][128 * 128];   // 2 x 32 KB
    __shared__ __align__(16) unsigned short Bs[2][128 * 128];   // 2 x 32 KB
    const unsigned short* A = x_bf + (size_t)b * 900 * 256;
    const unsigned short* B = tokens + (size_t)b * 1024 * 256;
    f32x4 acc[4][4];
    #pragma unroll
    for (int mi = 0; mi < 4; mi++)
        #pragma unroll
        for (int ni = 0; ni < 4; ni++) acc[mi][ni] = f32x4{0.f, 0.f, 0.f, 0.f};
    int r16 = lane & 15, r4 = lane >> 4;

    // stage one 128-K half of A and B: 8+8 gload16/thread, linear LDS dest,
    // pre-swizzled global source seg (rule 21: both-sides-or-neither).
    auto stageHalf = [&](int half) {
        #pragma unroll
        for (int i = 0; i < 8; i++) {
            int u = i * 256 + tid;                 // [0, 2048)
            int row = u >> 4, seg = u & 15;
            int ps = seg ^ (row & 15);             // swizzled source seg
            int ar = tm * 128 + row;
            if (ar > 899) ar = 899;                // clamp (stores guarded)
            gload16(&A[(size_t)ar * 256 + half * 128 + ps * 8],
                    &As[half][(i * 256 + w * 64) * 8]);
        }
        #pragma unroll
        for (int i = 0; i < 8; i++) {
            int u = i * 256 + tid;
            int row = u >> 4, seg = u & 15;
            int ps = seg ^ (row & 15);
            int nr = tn * 128 + row;
            gload16(&B[(size_t)nr * 256 + half * 128 + ps * 8],
                    &Bs[half][(i * 256 + w * 64) * 8]);
        }
    };

    stageHalf(0);
    stageHalf(1);
    asm volatile("s_waitcnt vmcnt(16)" ::: "memory");   // half 0 done, half 1 in flight
    __builtin_amdgcn_s_barrier();

    #pragma unroll 1
    for (int half = 0; half < 2; ++half) {
        #pragma unroll
        for (int kt = 0; kt < 4; ++kt) {
            bf16x8 a[4], bb[4];
            #pragma unroll
            for (int mi = 0; mi < 4; mi++) {
                int row = wm * 64 + mi * 16 + r16;
                a[mi] = *(const bf16x8*)&As[half][row * 128 +
                        (((kt * 4 + r4) ^ (row & 15)) * 8)];
            }
            #pragma unroll
            for (int ni = 0; ni < 4; ni++) {
                int row = wn * 64 + ni * 16 + r16;
                bb[ni] = *(const bf16x8*)&Bs[half][row * 128 +
                         (((kt * 4 + r4) ^ (row & 15)) * 8)];
            }
            #pragma unroll
            for (int mi = 0; mi < 4; mi++)
                #pragma unroll
                for (int ni = 0; ni < 4; ni++)
                    acc[mi][ni] = __builtin_amdgcn_mfma_f32_16x16x32_bf16(
                        a[mi], bb[ni], acc[mi][ni], 0, 0, 0);
        }
        if (half == 0) {
            asm volatile("s_waitcnt vmcnt(0)" ::: "memory");
            __builtin_amdgcn_s_barrier();
        }
    }

    float inv = __expf(-log_scale[0]);
    #pragma unroll
    for (int ni = 0; ni < 4; ni++) {
        int l = tn * 128 + wn * 64 + ni * 16 + r16;
        float tbv = tbias[b * 1024 + l];
        #pragma unroll
        for (int mi = 0; mi < 4; mi++) {
            #pragma unroll
            for (int e = 0; e < 4; e++) {
                int q = tm * 128 + wm * 64 + mi * 16 + r4 * 4 + e;
                if (q < 900) {
                    float vv = acc[mi][ni][e] * inv + tbv;
                    vv = fminf(fmaxf(vv, -50000.f), 50000.f);
                    __builtin_nontemporal_store(
                        vv, &out[((size_t)b * 900 + q) * 1024 + l]);
                }
            }
        }
    }
}

// ----------------------------------------------------------------
extern "C" void kernel_launch(void* const* d_in, const int* in_sizes, int n_in,
                              void* d_out, int out_size, void* d_ws, size_t ws_size,
                              hipStream_t stream)
{
    const float* x         = (const float*)d_in[0];
    const float* embedding = (const float*)d_in[1];
    const float* proj_w    = (const float*)d_in[2];
    const float* proj_b    = (const float*)d_in[3];
    const float* gate_w    = (const float*)d_in[4];
    const float* gate_b    = (const float*)d_in[5];
    const float* expert_w  = (const float*)d_in[6];
    const float* expert_b  = (const float*)d_in[7];
    const float* bias_lang = (const float*)d_in[8];
    const float* bias0     = (const float*)d_in[9];
    const float* log_scale = (const float*)d_in[10];
    float* out = (float*)d_out;

    size_t off = 0;
    char* base = (char*)d_ws;
    auto alloc = [&](size_t bytes) -> void* {
        void* p = base + off;
        off += (bytes + 255) & ~(size_t)255;
        return p;
    };
    unsigned short* emb_bf  = (unsigned short*)alloc((size_t)NROW * 768 * 2);     // 100MB
    unsigned short* x_bf    = (unsigned short*)alloc((size_t)14745600 * 2);       // 28MB
    unsigned short* wcatT   = (unsigned short*)alloc((size_t)2304 * 768 * 2);     // 3.4MB
    float* bcat             = (float*)alloc(2304 * 4);
    float* tbias            = (float*)alloc((size_t)NROW * 4);
    unsigned short* tokens  = (unsigned short*)alloc((size_t)NROW * 256 * 2);     // 32MB
    unsigned* cnt           = (unsigned*)alloc(8 * CSTRIDE * 4);
    unsigned* top2          = (unsigned*)alloc((size_t)NROW * 4);                 // 256KB
    float2* c2              = (float2*)alloc((size_t)NROW * 8);                   // 512KB
    unsigned* bidx          = (unsigned*)alloc((size_t)8 * CAP * 4);              // 2MB
    float* bscale           = (float*)alloc((size_t)8 * CAP * 4);                 // 2MB
    unsigned short* partial = (unsigned short*)alloc((size_t)2 * NROW * 256 * 2); // 64MB

    k_front<<<NB_K1 + NB_KX + NB_K0 + NB_KZ, 256, 0, stream>>>(
        x, embedding, proj_w, proj_b, gate_w, gate_b, expert_w, expert_b,
        bias_lang, bias0, x_bf, wcatT, bcat, cnt, emb_bf, top2, c2, tbias);
    kb_bucket<<<NROW / 256, 256, 0, stream>>>(top2, c2, cnt, bidx, bscale);
    dim3 g2(512, 8);
    k2_expert<<<g2, 512, 0, stream>>>(emb_bf, wcatT, bcat, cnt, bidx, bscale, partial);
    k2_proj<<<512, 512, 0, stream>>>(emb_bf, wcatT, bcat, partial, tokens);
    k3_logit<<<4096, 256, 0, stream>>>(x_bf, tokens, tbias, log_scale, out);
}

// Round 19
// 378.810 us; speedup vs baseline: 1.1701x; 1.1701x over previous
//
#include <hip/hip_runtime.h>
#include <hip/hip_bf16.h>

// BS=64 NQ=900 L=1024 D=768 H=256 E=8 TOPK=2 MOE_W=0.5
// out: (64,900,1024) f32
// Sparse MoE: heterogeneous fused front-end (k1 normalize+gate || x-cast ||
// W-transpose || misc in ONE launch), hierarchical bucketing, expert
// gather-GEMM (partial slots 0/1), proj GEMM fused with combine, logit GEMM
// (128^2 LDS 2-phase, XCD-pinned) — round-17 champion configuration.
// CLOSED EXPERIMENTS: k3 structural variants (counted-vmcnt r8, BM=256 r10,
// register-resident r11, occupancy-5 r15, full-K deep-phase r18) ALL lose to
// this form. GEMMs are register-pinned: min-waves above natural allocation
// spills (r14/r15, 3x slowdown).

typedef __attribute__((ext_vector_type(8))) short bf16x8;
typedef __attribute__((ext_vector_type(4))) float f32x4;

#define NROW 65536            // 64*1024 token rows
#define CAP  65536            // per-expert bucket capacity (worst case)
#define CSTRIDE 16            // cnt padding: one counter per 64B line
#define SWZ(r) ((((r) & 3) ^ (((r) >> 2) & 3)))

// fused front-end grid partition (k1 first: long pole starts immediately)
#define NB_K1 2048
#define NB_KX 14400
#define NB_K0 432             // 12 x 4 x 9
#define NB_KZ 9

__device__ __forceinline__ unsigned short f2bf(float f) {
    unsigned u = __builtin_bit_cast(unsigned, f);
    u += 0x7fffu + ((u >> 16) & 1u);   // RNE; inputs finite
    return (unsigned short)(u >> 16);
}
__device__ __forceinline__ float bf2f(unsigned short h) {
    unsigned u = ((unsigned)h) << 16;
    return __builtin_bit_cast(float, u);
}
__device__ __forceinline__ void gload16(const void* g, void* l) {
    __builtin_amdgcn_global_load_lds(
        (const __attribute__((address_space(1))) void*)g,
        (__attribute__((address_space(3))) void*)l, 16, 0, 0);
}
__device__ __forceinline__ unsigned cvt_pk_bf16(float a, float b) {
    unsigned r;
    asm("v_cvt_pk_bf16_f32 %0, %1, %2" : "=v"(r) : "v"(a), "v"(b));
    return r;
}

// ---------------------------------------------------------------- K_FRONT:
// blockIdx.x in [0, NB_K1)                      -> k1 normalize+gate
//              [NB_K1, NB_K1+NB_KX)             -> x -> bf16 cast
//              [NB_K1+NB_KX, +NB_K0)            -> W transpose tile
//              last NB_KZ                       -> bcat/cnt init
__global__ __launch_bounds__(256, 4) void k_front(
    const float* __restrict__ x, const float* __restrict__ emb_in,
    const float* __restrict__ proj_w, const float* __restrict__ proj_b,
    const float* __restrict__ gate_w, const float* __restrict__ gate_b,
    const float* __restrict__ expert_w, const float* __restrict__ expert_b,
    const float* __restrict__ bias_lang, const float* __restrict__ bias0,
    unsigned short* __restrict__ x_bf, unsigned short* __restrict__ wcatT,
    float* __restrict__ bcat, unsigned* __restrict__ cnt,
    unsigned short* __restrict__ emb_bf, unsigned* __restrict__ top2,
    float2* __restrict__ c2, float* __restrict__ tbias)
{
    __shared__ __align__(16) float smem[9 * 768];   // 27.6 KB, unioned per branch
    int bid = blockIdx.x, tid = threadIdx.x;

    if (bid < NB_K1) {
        // ---------------- k1_fused body ----------------
        float* gwT = smem;
        for (int i = tid; i < 768 * 8; i += 256) {
            int d = i >> 3, e = i & 7;
            gwT[e * 768 + d] = gate_w[i];
        }
        for (int i = tid; i < 768; i += 256)
            gwT[8 * 768 + i] = bias_lang[i];
        __syncthreads();

        int w = tid >> 6, lane = tid & 63;
        #pragma unroll 1
        for (int it = 0; it < 8; ++it) {
            int r = bid * 32 + w * 8 + it;
            const float4* rv = (const float4*)(emb_in + (size_t)r * 768);
            float4 v0 = rv[lane], v1 = rv[lane + 64], v2 = rv[lane + 128];
            float ss = v0.x*v0.x + v0.y*v0.y + v0.z*v0.z + v0.w*v0.w
                     + v1.x*v1.x + v1.y*v1.y + v1.z*v1.z + v1.w*v1.w
                     + v2.x*v2.x + v2.y*v2.y + v2.z*v2.z + v2.w*v2.w;
            #pragma unroll
            for (int m = 1; m < 64; m <<= 1) ss += __shfl_xor(ss, m, 64);
            float rn = rsqrtf(ss);

            unsigned long long q0 = (unsigned long long)cvt_pk_bf16(v0.x*rn, v0.y*rn) |
                                    ((unsigned long long)cvt_pk_bf16(v0.z*rn, v0.w*rn) << 32);
            unsigned long long q1 = (unsigned long long)cvt_pk_bf16(v1.x*rn, v1.y*rn) |
                                    ((unsigned long long)cvt_pk_bf16(v1.z*rn, v1.w*rn) << 32);
            unsigned long long q2 = (unsigned long long)cvt_pk_bf16(v2.x*rn, v2.y*rn) |
                                    ((unsigned long long)cvt_pk_bf16(v2.z*rn, v2.w*rn) << 32);
            unsigned long long* ob = (unsigned long long*)(emb_bf + (size_t)r * 768);
            __builtin_nontemporal_store(q0, ob + lane);
            __builtin_nontemporal_store(q1, ob + lane + 64);
            __builtin_nontemporal_store(q2, ob + lane + 128);

            float acc[9];
            #pragma unroll
            for (int i = 0; i < 9; i++) acc[i] = 0.f;
            const float4 vv[3] = { v0, v1, v2 };
            #pragma unroll
            for (int k = 0; k < 3; k++) {
                float4 v = vv[k];
                #pragma unroll
                for (int e = 0; e < 9; e++) {
                    float4 g = *(const float4*)&gwT[e * 768 + k * 256 + lane * 4];
                    acc[e] += v.x*g.x + v.y*g.y + v.z*g.z + v.w*g.w;
                }
            }
            #pragma unroll
            for (int m = 1; m < 64; m <<= 1) {
                #pragma unroll
                for (int i = 0; i < 9; i++) acc[i] += __shfl_xor(acc[i], m, 64);
            }
            if (lane == 0) {
                float g[8];
                #pragma unroll
                for (int e = 0; e < 8; e++) g[e] = acc[e] * rn + gate_b[e];
                float mx = g[0];
                #pragma unroll
                for (int e = 1; e < 8; e++) mx = fmaxf(mx, g[e]);
                float p[8], s = 0.f;
                #pragma unroll
                for (int e = 0; e < 8; e++) { p[e] = __expf(g[e] - mx); s += p[e]; }
                float inv = 0.5f / s;
                int i1 = 0;
                #pragma unroll
                for (int e = 1; e < 8; e++) if (g[e] > g[i1]) i1 = e;
                int i2 = (i1 == 0) ? 1 : 0;
                #pragma unroll
                for (int e = 0; e < 8; e++) if (e != i1 && g[e] > g[i2]) i2 = e;
                top2[r] = (unsigned)i1 | ((unsigned)i2 << 8);
                c2[r]   = make_float2(p[i1] * inv, p[i2] * inv);
                tbias[r] = acc[8] * rn + bias0[0];
            }
        }
    } else if (bid < NB_K1 + NB_KX) {
        // ---------------- kx_cast body ----------------
        int i = (bid - NB_K1) * 256 + tid;
        float4 v = ((const float4*)x)[i];
        unsigned long long o = (unsigned long long)cvt_pk_bf16(v.x, v.y) |
                               ((unsigned long long)cvt_pk_bf16(v.z, v.w) << 32);
        __builtin_nontemporal_store(o, (unsigned long long*)x_bf + i);
    } else if (bid < NB_K1 + NB_KX + NB_K0) {
        // ---------------- k0_wT body ----------------
        int u = bid - NB_K1 - NB_KX;            // [0, 432)
        int j = u / 48, rem = u % 48;
        int d0 = (rem % 12) * 64, h0 = (rem / 12) * 64;
        const float* W = (j < 8) ? expert_w + (size_t)j * 768 * 256 : proj_w;
        unsigned short (*s)[65] = (unsigned short (*)[65])smem;   // 8.3 KB of 27.6
        #pragma unroll
        for (int i = 0; i < 16; i++) {
            int d = i * 4 + (tid >> 6), h = tid & 63;
            s[d][h] = f2bf(W[(size_t)(d0 + d) * 256 + h0 + h]);
        }
        __syncthreads();
        #pragma unroll
        for (int i = 0; i < 16; i++) {
            int h = i * 4 + (tid >> 6), d = tid & 63;
            wcatT[(size_t)(j * 256 + h0 + h) * 768 + d0 + d] = s[d][h];
        }
    } else {
        // ---------------- kz_misc body ----------------
        int i = (bid - NB_K1 - NB_KX - NB_K0) * 256 + tid;
        if (i < 2304) {
            int jj = i >> 8, h = i & 255;
            bcat[i] = (jj < 8) ? expert_b[jj * 256 + h] : proj_b[h];
        }
        if (i < 8 * CSTRIDE) cnt[i] = 0;
    }
}

// ---------------------------------------------------------------- KB (hierarchical):
__global__ __launch_bounds__(256) void kb_bucket(
    const unsigned* __restrict__ top2, const float2* __restrict__ c2,
    unsigned* __restrict__ cnt, unsigned* __restrict__ bidx,
    float* __restrict__ bscale)
{
    __shared__ unsigned lcnt[8];
    __shared__ unsigned gbase[8];
    int tid = threadIdx.x, lane = tid & 63;
    if (tid < 8) lcnt[tid] = 0;
    __syncthreads();
    int r = blockIdx.x * 256 + tid;
    unsigned t = top2[r];
    float2 c = c2[r];
    int ii[2] = { (int)(t & 255), (int)((t >> 8) & 255) };
    float cc[2] = { c.x, c.y };
    unsigned lpos[2];
    #pragma unroll
    for (int slot = 0; slot < 2; slot++) {
        int myE = ii[slot];
        #pragma unroll 1
        for (int e = 0; e < 8; e++) {
            unsigned long long mask = __ballot(myE == e);
            if (myE == e) {
                int leader = __ffsll((unsigned long long)mask) - 1;
                unsigned base = 0;
                if (lane == leader)
                    base = atomicAdd(&lcnt[e], (unsigned)__popcll(mask));
                base = __shfl(base, leader, 64);
                lpos[slot] = base + (unsigned)__popcll(mask & ((1ull << lane) - 1ull));
            }
        }
    }
    __syncthreads();
    if (tid < 8) gbase[tid] = atomicAdd(&cnt[tid * CSTRIDE], lcnt[tid]);
    __syncthreads();
    #pragma unroll
    for (int slot = 0; slot < 2; slot++) {
        int e = ii[slot];
        unsigned p = gbase[e] + lpos[slot];
        bidx[(size_t)e * CAP + p]   = (unsigned)r | ((unsigned)slot << 16);
        bscale[(size_t)e * CAP + p] = cc[slot];
    }
}

// ---------------------------------------------------------------- K2E (experts 0..7):
__global__ __launch_bounds__(512, 2) void k2_expert(
    const unsigned short* __restrict__ emb_bf, const unsigned short* __restrict__ wcatT,
    const float* __restrict__ bcat, const unsigned* __restrict__ cnt,
    const unsigned* __restrict__ bidx, const float* __restrict__ bscale,
    unsigned short* __restrict__ partial)
{
    int e = blockIdx.y;                 // 0..7
    int tile = blockIdx.x;
    int cnt_e = (int)cnt[e * CSTRIDE];
    if (tile * 128 >= cnt_e) return;
    int tid = threadIdx.x, lane = tid & 63, w = tid >> 6;
    int wm = w >> 2, wn = w & 3;
    __shared__ __align__(16) unsigned short As[2][128 * 32];   // 16 KB
    __shared__ __align__(16) unsigned short Bs[2][256 * 32];   // 32 KB
    __shared__ unsigned sRow[128];
    __shared__ float sScale[128];
    if (tid < 128) {
        int gi = tile * 128 + tid;
        unsigned rs; float sc;
        if (gi < cnt_e) { rs = bidx[(size_t)e * CAP + gi];
                          sc = bscale[(size_t)e * CAP + gi]; }
        else            { rs = 0; sc = 0.f; }
        sRow[tid] = rs; sScale[tid] = sc;
    }
    __syncthreads();
    int r16 = lane & 15, r4 = lane >> 4;
    int srowA = tid >> 2, ssegA = (tid & 3) ^ SWZ(srowA);
    const unsigned short* aSrc =
        emb_bf + (size_t)(sRow[srowA] & 0xFFFFu) * 768 + ssegA * 8;
    const unsigned short* bBase = wcatT + (size_t)e * 256 * 768;

    auto stageA = [&](int kt, int buf) {
        gload16(aSrc + kt * 32, &As[buf][w * 512]);
    };
    auto stageB = [&](int kt, int buf) {
        #pragma unroll
        for (int i = 0; i < 2; i++) {
            int u = i * 512 + tid;
            int brow = u >> 2, seg = (u & 3) ^ SWZ(brow);
            gload16(&bBase[(size_t)brow * 768 + kt * 32 + seg * 8],
                    &Bs[buf][i * 4096 + w * 512]);
        }
    };

    f32x4 acc[4][4];
    #pragma unroll
    for (int mi = 0; mi < 4; mi++)
        #pragma unroll
        for (int ni = 0; ni < 4; ni++) acc[mi][ni] = f32x4{0.f, 0.f, 0.f, 0.f};

    stageA(0, 0); stageB(0, 0);
    __syncthreads();
    int buf = 0;
    #pragma unroll 1
    for (int kt = 0; kt < 24; ++kt) {
        if (kt < 23) { stageA(kt + 1, buf ^ 1); stageB(kt + 1, buf ^ 1); }
        bf16x8 a[4], b[4];
        #pragma unroll
        for (int mi = 0; mi < 4; mi++) {
            int arow = wm * 64 + mi * 16 + r16;
            a[mi] = *(const bf16x8*)&As[buf][arow * 32 + (r4 ^ SWZ(arow)) * 8];
        }
        #pragma unroll
        for (int ni = 0; ni < 4; ni++) {
            int brow = wn * 64 + ni * 16 + r16;
            b[ni] = *(const bf16x8*)&Bs[buf][brow * 32 + (r4 ^ SWZ(brow)) * 8];
        }
        #pragma unroll
        for (int mi = 0; mi < 4; mi++)
            #pragma unroll
            for (int ni = 0; ni < 4; ni++)
                acc[mi][ni] = __builtin_amdgcn_mfma_f32_16x16x32_bf16(
                    a[mi], b[ni], acc[mi][ni], 0, 0, 0);
        __syncthreads();
        buf ^= 1;
    }

    float bj[4];
    #pragma unroll
    for (int ni = 0; ni < 4; ni++) bj[ni] = bcat[e * 256 + wn * 64 + ni * 16 + r16];
    #pragma unroll
    for (int mi = 0; mi < 4; mi++) {
        #pragma unroll
        for (int e4 = 0; e4 < 4; e4++) {
            int rl = wm * 64 + mi * 16 + r4 * 4 + e4;
            if (tile * 128 + rl < cnt_e) {
                unsigned rs = sRow[rl];
                float sc = sScale[rl];
                unsigned rowg = rs & 0xFFFFu, slot = rs >> 16;
                #pragma unroll
                for (int ni = 0; ni < 4; ni++) {
                    int col = wn * 64 + ni * 16 + r16;
                    __builtin_nontemporal_store(
                        f2bf(sc * (acc[mi][ni][e4] + bj[ni])),
                        &partial[((size_t)slot * NROW + rowg) * 256 + col]);
                }
            }
        }
    }
}

// ---------------------------------------------------------------- K2P (proj + combine):
__global__ __launch_bounds__(512, 2) void k2_proj(
    const unsigned short* __restrict__ emb_bf, const unsigned short* __restrict__ wcatT,
    const float* __restrict__ bcat, const unsigned short* __restrict__ partial,
    unsigned short* __restrict__ tokens)
{
    int tile = blockIdx.x;
    int tid = threadIdx.x, lane = tid & 63, w = tid >> 6;
    int wm = w >> 2, wn = w & 3;
    int rowBase = tile * 128;
    __shared__ __align__(16) unsigned short As[2][128 * 32];
    __shared__ __align__(16) unsigned short Bs[2][256 * 32];
    int r16 = lane & 15, r4 = lane >> 4;
    int srowA = tid >> 2, ssegA = (tid & 3) ^ SWZ(srowA);
    const unsigned short* aSrc =
        emb_bf + (size_t)(rowBase + srowA) * 768 + ssegA * 8;
    const unsigned short* bBase = wcatT + (size_t)8 * 256 * 768;

    auto stageA = [&](int kt, int buf) {
        gload16(aSrc + kt * 32, &As[buf][w * 512]);
    };
    auto stageB = [&](int kt, int buf) {
        #pragma unroll
        for (int i = 0; i < 2; i++) {
            int u = i * 512 + tid;
            int brow = u >> 2, seg = (u & 3) ^ SWZ(brow);
            gload16(&bBase[(size_t)brow * 768 + kt * 32 + seg * 8],
                    &Bs[buf][i * 4096 + w * 512]);
        }
    };

    f32x4 acc[4][4];
    #pragma unroll
    for (int mi = 0; mi < 4; mi++)
        #pragma unroll
        for (int ni = 0; ni < 4; ni++) acc[mi][ni] = f32x4{0.f, 0.f, 0.f, 0.f};

    stageA(0, 0); stageB(0, 0);
    __syncthreads();
    int buf = 0;
    #pragma unroll 1
    for (int kt = 0; kt < 24; ++kt) {
        if (kt < 23) { stageA(kt + 1, buf ^ 1); stageB(kt + 1, buf ^ 1); }
        bf16x8 a[4], b[4];
        #pragma unroll
        for (int mi = 0; mi < 4; mi++) {
            int arow = wm * 64 + mi * 16 + r16;
            a[mi] = *(const bf16x8*)&As[buf][arow * 32 + (r4 ^ SWZ(arow)) * 8];
        }
        #pragma unroll
        for (int ni = 0; ni < 4; ni++) {
            int brow = wn * 64 + ni * 16 + r16;
            b[ni] = *(const bf16x8*)&Bs[buf][brow * 32 + (r4 ^ SWZ(brow)) * 8];
        }
        #pragma unroll
        for (int mi = 0; mi < 4; mi++)
            #pragma unroll
            for (int ni = 0; ni < 4; ni++)
                acc[mi][ni] = __builtin_amdgcn_mfma_f32_16x16x32_bf16(
                    a[mi], b[ni], acc[mi][ni], 0, 0, 0);
        __syncthreads();
        buf ^= 1;
    }

    const size_t S = (size_t)NROW * 256;
    float bj[4];
    #pragma unroll
    for (int ni = 0; ni < 4; ni++) bj[ni] = bcat[8 * 256 + wn * 64 + ni * 16 + r16];
    #pragma unroll
    for (int mi = 0; mi < 4; mi++) {
        #pragma unroll
        for (int e4 = 0; e4 < 4; e4++) {
            int rl = wm * 64 + mi * 16 + r4 * 4 + e4;
            size_t rowg = rowBase + rl;
            #pragma unroll
            for (int ni = 0; ni < 4; ni++) {
                int col = wn * 64 + ni * 16 + r16;
                float p0 = bf2f(partial[rowg * 256 + col]);
                float p1 = bf2f(partial[S + rowg * 256 + col]);
                float v = 0.5f * (acc[mi][ni][e4] + bj[ni]) + p0 + p1;
                __builtin_nontemporal_store(f2bf(v), &tokens[rowg * 256 + col]);
            }
        }
    }
}

// ---------------------------------------------------------------- K3 (128^2 LDS, XCD-pinned):
// (256,4): VGPR 68, no spill. Round-17 champion form — do not restructure.
__global__ __launch_bounds__(256, 4) void k3_logit(
    const unsigned short* __restrict__ x_bf, const unsigned short* __restrict__ tokens,
    const float* __restrict__ tbias, const float* __restrict__ log_scale,
    float* __restrict__ out)
{
    int wgid = blockIdx.x;
    int xcd = wgid & 7, slot = wgid >> 3;
    int b = xcd + 8 * (slot >> 6);
    int t64 = slot & 63;
    int tm = t64 >> 3, tn = t64 & 7;

    int tid = threadIdx.x, lane = tid & 63, w = tid >> 6;
    int wm = w >> 1, wn = w & 1;
    __shared__ __align__(16) unsigned short As[2][128 * 32];
    __shared__ __align__(16) unsigned short Bs[2][128 * 32];
    const unsigned short* A = x_bf + (size_t)b * 900 * 256;
    const unsigned short* B = tokens + (size_t)b * 1024 * 256;
    f32x4 acc[4][4];
    #pragma unroll
    for (int mi = 0; mi < 4; mi++)
        #pragma unroll
        for (int ni = 0; ni < 4; ni++) acc[mi][ni] = f32x4{0.f, 0.f, 0.f, 0.f};
    int r16 = lane & 15, r4 = lane >> 4;

    auto stage = [&](int kt, int buf) {
        #pragma unroll
        for (int i = 0; i < 2; i++) {
            int u = i * 256 + tid;
            int row = u >> 2, seg = (u & 3) ^ SWZ(row);
            int ar = tm * 128 + row;
            if (ar > 899) ar = 899;
            gload16(&A[(size_t)ar * 256 + kt * 32 + seg * 8],
                    &As[buf][i * 2048 + w * 512]);
            int nr = tn * 128 + row;
            gload16(&B[(size_t)nr * 256 + kt * 32 + seg * 8],
                    &Bs[buf][i * 2048 + w * 512]);
        }
    };

    stage(0, 0);
    __syncthreads();
    int buf = 0;
    #pragma unroll 1
    for (int kt = 0; kt < 8; ++kt) {
        if (kt < 7) stage(kt + 1, buf ^ 1);
        bf16x8 a[4], bb[4];
        #pragma unroll
        for (int mi = 0; mi < 4; mi++) {
            int row = wm * 64 + mi * 16 + r16;
            a[mi] = *(const bf16x8*)&As[buf][row * 32 + (r4 ^ SWZ(row)) * 8];
        }
        #pragma unroll
        for (int ni = 0; ni < 4; ni++) {
            int row = wn * 64 + ni * 16 + r16;
            bb[ni] = *(const bf16x8*)&Bs[buf][row * 32 + (r4 ^ SWZ(row)) * 8];
        }
        #pragma unroll
        for (int mi = 0; mi < 4; mi++)
            #pragma unroll
            for (int ni = 0; ni < 4; ni++)
                acc[mi][ni] = __builtin_amdgcn_mfma_f32_16x16x32_bf16(
                    a[mi], bb[ni], acc[mi][ni], 0, 0, 0);
        __syncthreads();
        buf ^= 1;
    }
    float inv = __expf(-log_scale[0]);
    #pragma unroll
    for (int ni = 0; ni < 4; ni++) {
        int l = tn * 128 + wn * 64 + ni * 16 + r16;
        float tbv = tbias[b * 1024 + l];
        #pragma unroll
        for (int mi = 0; mi < 4; mi++) {
            #pragma unroll
            for (int e = 0; e < 4; e++) {
                int q = tm * 128 + wm * 64 + mi * 16 + r4 * 4 + e;
                if (q < 900) {
                    float vv = acc[mi][ni][e] * inv + tbv;
                    vv = fminf(fmaxf(vv, -50000.f), 50000.f);
                    __builtin_nontemporal_store(
                        vv, &out[((size_t)b * 900 + q) * 1024 + l]);
                }
            }
        }
    }
}

// ----------------------------------------------------------------
extern "C" void kernel_launch(void* const* d_in, const int* in_sizes, int n_in,
                              void* d_out, int out_size, void* d_ws, size_t ws_size,
                              hipStream_t stream)
{
    const float* x         = (const float*)d_in[0];
    const float* embedding = (const float*)d_in[1];
    const float* proj_w    = (const float*)d_in[2];
    const float* proj_b    = (const float*)d_in[3];
    const float* gate_w    = (const float*)d_in[4];
    const float* gate_b    = (const float*)d_in[5];
    const float* expert_w  = (const float*)d_in[6];
    const float* expert_b  = (const float*)d_in[7];
    const float* bias_lang = (const float*)d_in[8];
    const float* bias0     = (const float*)d_in[9];
    const float* log_scale = (const float*)d_in[10];
    float* out = (float*)d_out;

    size_t off = 0;
    char* base = (char*)d_ws;
    auto alloc = [&](size_t bytes) -> void* {
        void* p = base + off;
        off += (bytes + 255) & ~(size_t)255;
        return p;
    };
    unsigned short* emb_bf  = (unsigned short*)alloc((size_t)NROW * 768 * 2);     // 100MB
    unsigned short* x_bf    = (unsigned short*)alloc((size_t)14745600 * 2);       // 28MB
    unsigned short* wcatT   = (unsigned short*)alloc((size_t)2304 * 768 * 2);     // 3.4MB
    float* bcat             = (float*)alloc(2304 * 4);
    float* tbias            = (float*)alloc((size_t)NROW * 4);
    unsigned short* tokens  = (unsigned short*)alloc((size_t)NROW * 256 * 2);     // 32MB
    unsigned* cnt           = (unsigned*)alloc(8 * CSTRIDE * 4);
    unsigned* top2          = (unsigned*)alloc((size_t)NROW * 4);                 // 256KB
    float2* c2              = (float2*)alloc((size_t)NROW * 8);                   // 512KB
    unsigned* bidx          = (unsigned*)alloc((size_t)8 * CAP * 4);              // 2MB
    float* bscale           = (float*)alloc((size_t)8 * CAP * 4);                 // 2MB
    unsigned short* partial = (unsigned short*)alloc((size_t)2 * NROW * 256 * 2); // 64MB

    k_front<<<NB_K1 + NB_KX + NB_K0 + NB_KZ, 256, 0, stream>>>(
        x, embedding, proj_w, proj_b, gate_w, gate_b, expert_w, expert_b,
        bias_lang, bias0, x_bf, wcatT, bcat, cnt, emb_bf, top2, c2, tbias);
    kb_bucket<<<NROW / 256, 256, 0, stream>>>(top2, c2, cnt, bidx, bscale);
    dim3 g2(512, 8);
    k2_expert<<<g2, 512, 0, stream>>>(emb_bf, wcatT, bcat, cnt, bidx, bscale, partial);
    k2_proj<<<512, 512, 0, stream>>>(emb_bf, wcatT, bcat, partial, tokens);
    k3_logit<<<4096, 256, 0, stream>>>(x_bf, tokens, tbias, log_scale, out);
}